// Round 9
// baseline (63.485 us; speedup 1.0000x reference)
//
#include <hip/hip_runtime.h>

#define NQ 14
#define BLOCK 512
#define NG 28
#define NF2 16  // f32x2 regs per thread (32 amps)

typedef float f32x2 __attribute__((ext_vector_type(2)));
__device__ __forceinline__ f32x2 mk2(float a, float b) { f32x2 r; r.x = a; r.y = b; return r; }

// ---------------- compile-time schedule (lazy-CNOT folding) ----------------
struct Sched { unsigned m[NG]; unsigned r[NG]; unsigned fr[NQ]; };

constexpr Sched build_sched() {
  Sched sc{};
  unsigned col[NQ] = {}, rowinv[NQ] = {};
  for (int p = 0; p < NQ; ++p) { col[p] = 1u << p; rowinv[p] = 1u << p; }
  int g = 0;
  for (int l = 0; l < 2; ++l) {
    for (int w = 0; w < NQ; ++w) { int p = NQ - 1 - w; sc.m[g] = col[p]; sc.r[g] = rowinv[p]; ++g; }
    for (int w = 0; w < NQ; ++w) {
      int tgt = (w + 1) % NQ; int pc = NQ - 1 - w, pt = NQ - 1 - tgt;
      col[pc] ^= col[pt]; rowinv[pt] ^= rowinv[pc];
    }
  }
  for (int w = 0; w < NQ; ++w) sc.fr[w] = rowinv[NQ - 1 - w];
  return sc;
}
constexpr Sched SC = build_sched();

// Layer-0 weights absorbed into fill. Remaining g14..g27 in ORIGINAL order:
//   P1: g14-17 span{9..13}  P2: g18-21 {5..9}  P3: g22-25 {1..5}  P4: g26-27 {0,1,2,12,13}
constexpr unsigned SPAN[4] = {0x3E00u, 0x03E0u, 0x003Eu, 0x3007u};

// local maps: l = (p<<1)|e  (no bit duplication — clean field extracts)
constexpr unsigned lmap1(unsigned v) { return ((v >> 9) & 1u) | (((v >> 10) & 15u) << 1); }  // e=i9  p=i10..13
constexpr unsigned lmap2(unsigned v) { return ((v >> 9) & 1u) | (((v >> 5) & 15u) << 1); }   // e=i9  p=i5..8
constexpr unsigned lmap3(unsigned v) { return ((v >> 5) & 1u) | (((v >> 1) & 15u) << 1); }   // e=i5  p=i1..4
constexpr unsigned lmap4(unsigned v) {                                                       // e=i1  p=(i2,i0,i12,i13)
  return ((v >> 1) & 1u) | (((v >> 2) & 1u) << 1) | ((v & 1u) << 2) | (((v >> 12) & 3u) << 3);
}

// ---------- phase layouts: (t<512, p<16, e<2) -> state i ----------
__host__ __device__ constexpr unsigned i1(unsigned t, unsigned p, unsigned e) {
  return t | (e << 9) | (p << 10);
}
__host__ __device__ constexpr unsigned i2(unsigned t, unsigned p, unsigned e) {
  return (t & 31u) | (p << 5) | (e << 9) | ((t >> 5) << 10);
}
__host__ __device__ constexpr unsigned i3(unsigned t, unsigned p, unsigned e) {
  return (t & 1u) | (p << 1) | (e << 5) | ((t >> 1) << 6);
}
__host__ __device__ constexpr unsigned i4(unsigned t, unsigned p, unsigned e) {
  return ((p >> 1) & 1u) | (e << 1) | ((p & 1u) << 2) | (t << 3) | (((p >> 2) & 3u) << 12);
}
__host__ __device__ constexpr unsigned base1(unsigned t) { return t; }
__host__ __device__ constexpr unsigned base2(unsigned t) { return (t & 31u) | ((t >> 5) << 10); }
__host__ __device__ constexpr unsigned base3(unsigned t) { return (t & 1u) | ((t >> 1) << 6); }
__host__ __device__ constexpr unsigned base4(unsigned t) { return t << 3; }

// ---------- canonical storage maps (dword addr of state i) ----------
__host__ __device__ constexpr unsigned dwT1(unsigned i) {
  return ((i >> 9) & 1u) + 2u * ((i >> 10) & 1u)
       + 4u * ((((i >> 11) & 7u) ^ (i & 7u)) | ((i & 511u) << 3));
}
__host__ __device__ constexpr unsigned dwT2(unsigned i) {
  return ((i >> 5) & 1u) + 2u * ((i >> 6) & 1u)
       + 4u * ((((i >> 7) & 7u) ^ (i & 7u)) | ((i & 31u) << 3) | (((i >> 10) & 15u) << 8));
}
__host__ __device__ constexpr unsigned dwT3(unsigned i) {
  return ((i >> 1) & 1u) + 2u * ((i >> 2) & 1u)
       + 4u * ((((i >> 3) & 7u) ^ ((i >> 6) & 7u)) | ((i & 1u) << 3) | (((i >> 6) & 255u) << 4));
}

// ---------- device decompositions (same fns evaluated in the asserts) ----------
__host__ __device__ constexpr unsigned W1(unsigned t, unsigned k) {            // float4 idx
  return (t << 3) | (k ^ (t & 7u));
}
__host__ __device__ constexpr unsigned BASER1(unsigned t) {                    // f32x2 slot base
  return ((t >> 5) & 1u) | (((((t >> 6) & 7u) ^ (t & 7u))) << 1) | ((t & 31u) << 4);
}
__host__ __device__ constexpr unsigned W2(unsigned t, unsigned j, unsigned e) {  // float4 idx
  return ((t & 7u) ^ (j | (e << 2))) | ((t & 31u) << 3) | (((t >> 5) & 15u) << 8);
}
__host__ __device__ constexpr unsigned CR2(unsigned t) {                       // f32x2 slot base
  return ((t >> 1) & 1u) | (((((t >> 2) & 7u) ^ (t & 1u))) << 1) | ((t & 1u) << 4)
       | (((t >> 5) & 15u) << 9);
}
__host__ __device__ constexpr unsigned VR2(unsigned p) { return ((p & 3u) << 2) ^ (p << 5); }
__host__ __device__ constexpr unsigned W3(unsigned t, unsigned j, unsigned e) {  // float4 idx
  return (((t >> 1) & 7u) ^ (j | (e << 2))) | ((t & 1u) << 3) | ((t >> 1) << 4);
}
__host__ __device__ constexpr unsigned R3(unsigned t, unsigned m) {            // float4 idx
  return (((t & 7u) ^ ((t >> 3) & 7u)) | ((t >> 3) << 4)) | (((m & 1u) << 3) | ((m >> 1) << 10));
}

// ---------------- machine checks ----------------
constexpr bool sched_ok() {
  for (int g = 0; g < 14; ++g)  // absorbability of layer-0
    if (SC.m[g] != (1u << (13 - g)) || SC.r[g] != (1u << (13 - g))) return false;
  for (int g = 14; g < 28; ++g) {
    const int ph = (g < 18) ? 0 : (g < 22) ? 1 : (g < 26) ? 2 : 3;
    if (SC.m[g] & ~SPAN[ph]) return false;
    unsigned lm = 0, lr = 0;
    if (ph == 0) { lm = lmap1(SC.m[g]); lr = lmap1(SC.r[g]); }
    if (ph == 1) { lm = lmap2(SC.m[g]); lr = lmap2(SC.r[g]); }
    if (ph == 2) { lm = lmap3(SC.m[g]); lr = lmap3(SC.r[g]); }
    if (ph == 3) { lm = lmap4(SC.m[g]); lr = lmap4(SC.r[g]); }
    if (lm == 0 || lm >= 32) return false;
    if (!(__builtin_popcount(lm & lr) & 1)) return false;
  }
  return true;  // execution order == original order
}
static_assert(sched_ok(), "schedule invalid");

constexpr unsigned iP(int ph, unsigned t, unsigned p, unsigned e) {
  return ph == 0 ? i1(t, p, e) : ph == 1 ? i2(t, p, e) : ph == 2 ? i3(t, p, e) : i4(t, p, e);
}
constexpr bool layouts_ok() {
  for (int ph = 0; ph < 4; ++ph) {
    unsigned acc = 0;
    for (int k = 0; k < 14; ++k) {
      unsigned t = 0, p = 0, e = 0;
      if (k < 9) t = 1u << k; else if (k < 13) p = 1u << (k - 9); else e = 1;
      const unsigned v = iP(ph, t, p, e);
      if (__builtin_popcount(v) != 1 || (acc & v)) return false;
      acc |= v;
    }
    if (acc != 0x3FFFu) return false;
  }
  for (unsigned t = 0; t < 512; ++t) {
    if (base1(t) != i1(t, 0, 0) || base2(t) != i2(t, 0, 0)) return false;
    if (base3(t) != i3(t, 0, 0) || base4(t) != i4(t, 0, 0)) return false;
  }
  return true;
}
static_assert(layouts_ok(), "phase layouts invalid");

constexpr bool stmap_bij(int which) {
  bool hit[16384] = {};
  for (unsigned i = 0; i < 16384; ++i) {
    const unsigned a = which == 0 ? dwT1(i) : which == 1 ? dwT2(i) : dwT3(i);
    if (a >= 16384u || hit[a]) return false;
    hit[a] = true;
  }
  return true;
}
static_assert(stmap_bij(0), "dwT1 not bijective");
static_assert(stmap_bij(1), "dwT2 not bijective");
static_assert(stmap_bij(2), "dwT3 not bijective");

// device decomposition == canonical map, exhaustive per pattern
constexpr bool chk(int pat, unsigned t0, unsigned t1) {
  for (unsigned t = t0; t < t1; ++t) {
    if (pat == 0) {  // T1 write: b128 over (e, p&1), k = p>>1
      for (unsigned k = 0; k < 8; ++k) {
        const unsigned B = 4u * W1(t, k);
        if (B + 3 >= 16384u) return false;
        for (unsigned q = 0; q < 2; ++q)
          for (unsigned e = 0; e < 2; ++e)
            if (dwT1(i1(t, 2 * k + q, e)) != B + 2 * q + e) return false;
      }
    } else if (pat == 1) {  // T1 read: b64 over e
      for (unsigned p = 0; p < 16; ++p) {
        const unsigned s = BASER1(t) | (p << 9);
        if (2 * s + 1 >= 16384u) return false;
        for (unsigned e = 0; e < 2; ++e)
          if (dwT1(i2(t, p, e)) != 2 * s + e) return false;
      }
    } else if (pat == 2) {  // T2 write: b128 over (p&3), per (j = p>>2, e)
      for (unsigned j = 0; j < 4; ++j)
        for (unsigned e = 0; e < 2; ++e) {
          const unsigned B = 4u * W2(t, j, e);
          if (B + 3 >= 16384u) return false;
          for (unsigned d = 0; d < 4; ++d)
            if (dwT2(i2(t, 4 * j + d, e)) != B + d) return false;
        }
    } else if (pat == 3) {  // T2 read: b64 over e
      for (unsigned p = 0; p < 16; ++p) {
        const unsigned s = CR2(t) ^ VR2(p);
        if (2 * s + 1 >= 16384u) return false;
        for (unsigned e = 0; e < 2; ++e)
          if (dwT2(i3(t, p, e)) != 2 * s + e) return false;
      }
    } else if (pat == 4) {  // T3 write: b128 over (p&3), per (j = p>>2, e)
      for (unsigned j = 0; j < 4; ++j)
        for (unsigned e = 0; e < 2; ++e) {
          const unsigned B = 4u * W3(t, j, e);
          if (B + 3 >= 16384u) return false;
          for (unsigned d = 0; d < 4; ++d)
            if (dwT3(i3(t, 4 * j + d, e)) != B + d) return false;
        }
    } else {  // T3 read: b128 over (e, p&1), m = p>>1
      for (unsigned m = 0; m < 8; ++m) {
        const unsigned B = 4u * R3(t, m);
        if (B + 3 >= 16384u) return false;
        for (unsigned q = 0; q < 2; ++q)
          for (unsigned e = 0; e < 2; ++e)
            if (dwT3(i4(t, 2 * m + q, e)) != B + 2 * q + e) return false;
      }
    }
  }
  return true;
}
static_assert(chk(0, 0, 256) && chk(0, 256, 512), "T1w addr");
static_assert(chk(1, 0, 256) && chk(1, 256, 512), "T1r addr");
static_assert(chk(2, 0, 256) && chk(2, 256, 512), "T2w addr");
static_assert(chk(3, 0, 256) && chk(3, 256, 512), "T2r addr");
static_assert(chk(4, 0, 256) && chk(4, 256, 512), "T3w addr");
static_assert(chk(5, 0, 256) && chk(5, 256, 512), "T3r addr");

// bank balance at the bandwidth floor: b128 <=8 lanes/group, b64 <=4 lanes/pair
constexpr bool banks_ok() {
  for (unsigned W = 0; W < 8; ++W) {
    for (unsigned s = 0; s < 8; ++s) {  // 8-step b128 patterns
      int c1[8] = {}, c2[8] = {}, c3[8] = {}, c4[8] = {};
      for (unsigned l = 0; l < 64; ++l) {
        const unsigned t = W * 64u + l;
        if (++c1[W1(t, s) & 7u] > 8) return false;
        if (++c2[W2(t, s & 3u, s >> 2) & 7u] > 8) return false;
        if (++c3[W3(t, s & 3u, s >> 2) & 7u] > 8) return false;
        if (++c4[R3(t, s) & 7u] > 8) return false;
      }
    }
    for (unsigned p = 0; p < 16; ++p) {  // 16-step b64 patterns
      int c1[16] = {}, c2[16] = {};
      for (unsigned l = 0; l < 64; ++l) {
        const unsigned t = W * 64u + l;
        if (++c1[(BASER1(t) | (p << 9)) & 15u] > 4) return false;
        if (++c2[(CR2(t) ^ VR2(p)) & 15u] > 4) return false;
      }
    }
  }
  return true;
}
static_assert(banks_ok(), "bank balance");

// ---------------- packed register butterfly (5-bit local) ----------------
template <unsigned MU, unsigned RHO>
__device__ __forceinline__ void gate_pk(f32x2* v, const float cg, const float sb) {
  const f32x2 C = mk2(cg, cg);
  constexpr unsigned M2 = MU >> 1;
  constexpr bool ODD = (MU & 1u) != 0;
  if constexpr (!ODD) {
    constexpr unsigned LSB = M2 & (0u - M2);
#pragma unroll
    for (unsigned p = 0; p < NF2; ++p) {
      if (p & LSB) continue;
      const unsigned q = p ^ M2;
      const int s0 = __builtin_popcount((2u * p) & RHO) & 1;
      const int s1 = __builtin_popcount((2u * p + 1u) & RHO) & 1;
      const f32x2 Sp = mk2(s0 ? -sb : sb, s1 ? -sb : sb);
      const f32x2 Xp = v[p], Xq = v[q];
      v[p] = C * Xp - Sp * Xq;
      v[q] = C * Xq + Sp * Xp;
    }
  } else if constexpr (M2 == 0) {
#pragma unroll
    for (unsigned p = 0; p < NF2; ++p) {
      const int s0 = __builtin_popcount((2u * p) & RHO) & 1;
      const f32x2 Sp = mk2(s0 ? -sb : sb, s0 ? sb : -sb);
      const f32x2 X = v[p];
      v[p] = C * X - Sp * mk2(X.y, X.x);
    }
  } else {
    constexpr unsigned LSB = M2 & (0u - M2);
#pragma unroll
    for (unsigned p = 0; p < NF2; ++p) {
      if (p & LSB) continue;
      const unsigned q = p ^ M2;
      const int s0 = __builtin_popcount((2u * p) & RHO) & 1;
      const int s1 = __builtin_popcount((2u * p + 1u) & RHO) & 1;
      const f32x2 Sp = mk2(s0 ? -sb : sb, s1 ? -sb : sb);
      const f32x2 Xp = v[p], Xq = v[q];
      const f32x2 T = Sp * Xp;
      v[p] = C * Xp - Sp * mk2(Xq.y, Xq.x);
      v[q] = C * Xq + mk2(T.y, T.x);
    }
  }
}

__global__ __launch_bounds__(BLOCK, 4) void qnn_kernel(
    const float* __restrict__ x, const float* __restrict__ wts,
    float* __restrict__ out) {
  __shared__ float4 S4[4096];  // 64 KB
  float* const S = (float*)S4;
  float4* const F4 = S4;
  f32x2* const Fv = (f32x2*)S4;
  const unsigned t = threadIdx.x;
  const int b = blockIdx.x;

  f32x2 v2[NF2];

  // ---- Fill: RY(x + weights[0]) product state, P1 layout ----
  // thread bits 0..8 = wires 13..5; e(i9)=wire4; p bit k (i10+k) = wire 3-k.
  {
    float cxx[NQ], sxx[NQ];
#pragma unroll
    for (int w = 0; w < NQ; ++w) {
      const float ang = 0.5f * (x[b * NQ + w] + wts[w]);
      sxx[w] = __sinf(ang);
      cxx[w] = __cosf(ang);
    }
    float pl = 1.0f;
#pragma unroll
    for (int bb = 0; bb < 9; ++bb) pl *= ((t >> bb) & 1) ? sxx[13 - bb] : cxx[13 - bb];
    v2[0] = mk2(pl * cxx[4], pl * sxx[4]);
#pragma unroll
    for (int k = 0; k < 4; ++k) {
      const int K = 1 << k;
      const float sk = sxx[3 - k], ck = cxx[3 - k];
#pragma unroll
      for (int j = K - 1; j >= 0; --j) {
        v2[j | K] = v2[j] * mk2(sk, sk);
        v2[j] = v2[j] * mk2(ck, ck);
      }
    }
  }

#define RUN_GATE(LM, G, BASEPAR)                                          \
  {                                                                       \
    const float ang = 0.5f * wts[G];                                      \
    const float sn = __sinf(ang), cs = __cosf(ang);                       \
    const float sb =                                                      \
        (__builtin_popcount((BASEPAR) & SC.r[G]) & 1) ? -sn : sn;         \
    gate_pk<LM(SC.m[G]), LM(SC.r[G])>(v2, cs, sb);                        \
  }

  // ---------------- Phase 1: span {9..13} ----------------
  {
    const unsigned bs = base1(t);
    RUN_GATE(lmap1, 14, bs) RUN_GATE(lmap1, 15, bs)
    RUN_GATE(lmap1, 16, bs) RUN_GATE(lmap1, 17, bs)
#pragma unroll
    for (unsigned k = 0; k < 8; ++k) {  // b128: +2q+e
      float4 w4;
      w4.x = v2[2 * k].x; w4.y = v2[2 * k].y;
      w4.z = v2[2 * k + 1].x; w4.w = v2[2 * k + 1].y;
      F4[W1(t, k)] = w4;
    }
  }
  __syncthreads();  // A

  // ---------------- Phase 2: span {5..9} ----------------
  {
    const unsigned bs = base2(t);
    const unsigned rb = BASER1(t);
#pragma unroll
    for (unsigned p = 0; p < NF2; ++p) v2[p] = Fv[rb | (p << 9)];  // b64
    RUN_GATE(lmap2, 18, bs) RUN_GATE(lmap2, 19, bs)
    RUN_GATE(lmap2, 20, bs) RUN_GATE(lmap2, 21, bs)
  }
  __syncthreads();  // B: T1 reads drained
  {
#pragma unroll
    for (unsigned j = 0; j < 4; ++j) {  // b128 x2: +d over p&3, per e
      float4 w0, w1;
      w0.x = v2[4 * j].x; w0.y = v2[4 * j + 1].x; w0.z = v2[4 * j + 2].x; w0.w = v2[4 * j + 3].x;
      w1.x = v2[4 * j].y; w1.y = v2[4 * j + 1].y; w1.z = v2[4 * j + 2].y; w1.w = v2[4 * j + 3].y;
      F4[W2(t, j, 0)] = w0;
      F4[W2(t, j, 1)] = w1;
    }
  }
  __syncthreads();  // C

  // ---------------- Phase 3: span {1..5} ----------------
  {
    const unsigned bs = base3(t);
    const unsigned rb = CR2(t);
#pragma unroll
    for (unsigned p = 0; p < NF2; ++p) v2[p] = Fv[rb ^ VR2(p)];  // b64
    RUN_GATE(lmap3, 22, bs) RUN_GATE(lmap3, 23, bs)
    RUN_GATE(lmap3, 24, bs) RUN_GATE(lmap3, 25, bs)
  }
  __syncthreads();  // D: T2 reads drained
  {
#pragma unroll
    for (unsigned j = 0; j < 4; ++j) {  // b128 x2: +d over p&3, per e
      float4 w0, w1;
      w0.x = v2[4 * j].x; w0.y = v2[4 * j + 1].x; w0.z = v2[4 * j + 2].x; w0.w = v2[4 * j + 3].x;
      w1.x = v2[4 * j].y; w1.y = v2[4 * j + 1].y; w1.z = v2[4 * j + 2].y; w1.w = v2[4 * j + 3].y;
      F4[W3(t, j, 0)] = w0;
      F4[W3(t, j, 1)] = w1;
    }
  }
  __syncthreads();  // E

  // -------- Phase 4: span {0,1,2,12,13} + measurement --------
  float ex[NQ];
  {
    const unsigned bs = base4(t);
#pragma unroll
    for (unsigned m = 0; m < 8; ++m) {  // b128: +2q+e
      const float4 r4 = F4[R3(t, m)];
      v2[2 * m] = mk2(r4.x, r4.y);
      v2[2 * m + 1] = mk2(r4.z, r4.w);
    }
    RUN_GATE(lmap4, 26, bs) RUN_GATE(lmap4, 27, bs)

    // q = v^2; WHT over 4 p-bits; e folded into extraction
#pragma unroll
    for (unsigned p = 0; p < NF2; ++p) v2[p] = v2[p] * v2[p];
#pragma unroll
    for (int k = 0; k < 4; ++k) {
      const unsigned K = 1u << k;
#pragma unroll
      for (unsigned p = 0; p < NF2; ++p) {
        if (p & K) continue;
        const f32x2 A = v2[p], Bv = v2[p ^ K];
        v2[p] = A + Bv;
        v2[p ^ K] = A - Bv;
      }
    }
#pragma unroll
    for (int w = 0; w < NQ; ++w) {
      const unsigned ls = lmap4(SC.fr[w]);
      const f32x2 Wv = v2[ls >> 1];
      const float coef = (ls & 1u) ? (Wv.x - Wv.y) : (Wv.x + Wv.y);
      const int tf = __builtin_popcount(bs & SC.fr[w]) & 1;
      ex[w] = tf ? -coef : coef;
    }
  }
  __syncthreads();  // F: T3 reads drained; S reusable

  // ---------------- two-stage LDS reduction ----------------
  // Stage A: thread t row = dwords [16t,16t+16): ex[2q],ex[2q+1] at slot t*8+(q^((t>>1)&7))
  {
#pragma unroll
    for (unsigned q = 0; q < 7; ++q)
      Fv[t * 8u + (q ^ ((t >> 1) & 7u))] = mk2(ex[2 * q], ex[2 * q + 1]);
  }
  __syncthreads();  // G
  {
    const unsigned w = t & 15u, g = t >> 4;  // g < 32
    if (w < NQ) {
      float acc = 0.0f;
#pragma unroll
      for (unsigned k = 0; k < 16; ++k)
        acc += S[(g * 16u + k) * 16u + (((w & 14u) ^ (k & 14u)) + (w & 1u))];
      S[8192u + w * 32u + g] = acc;
    }
  }
  __syncthreads();  // H
  if (t < NQ) {
    float r = 0.0f;
#pragma unroll
    for (unsigned j = 0; j < 8; ++j) {
      const float4 r4 = F4[2048u + t * 8u + j];
      r += r4.x + r4.y + r4.z + r4.w;
    }
    out[b * NQ + t] = r;
  }
#undef RUN_GATE
}

extern "C" void kernel_launch(void* const* d_in, const int* in_sizes, int n_in,
                              void* d_out, int out_size, void* d_ws, size_t ws_size,
                              hipStream_t stream) {
  const float* x = (const float*)d_in[0];        // (B, 14) fp32
  const float* weights = (const float*)d_in[1];  // (2, 14) fp32
  float* out = (float*)d_out;                    // (B, 14) fp32
  const int B = in_sizes[0] / NQ;
  qnn_kernel<<<B, BLOCK, 0, stream>>>(x, weights, out);
}